// Round 1
// baseline (92.899 us; speedup 1.0000x reference)
//
#include <hip/hip_runtime.h>
#include <math.h>

// Problem constants: both clouds are 16384 x float2.
#define NPTS  16384
#define BLK   256          // threads per block
#define Q     4            // queries per thread
#define QB    (NPTS / (BLK * Q))   // 16 query-blocks per direction
#define TCH   32                   // target chunks per direction
#define CHUNK (NPTS / TCH)         // 512 targets per chunk

// ws[0 .. 2*NPTS) : per-point min squared distance as uint-ordered fp32 bits
//   [0, NPTS)        -> min over ref for each render point (dir 0)
//   [NPTS, 2*NPTS)   -> min over render for each ref point (dir 1)

__global__ void cc_init_kernel(unsigned int* __restrict__ ws, float* __restrict__ out) {
    int i = blockIdx.x * blockDim.x + threadIdx.x;
    if (i < 2 * NPTS) ws[i] = 0x7F800000u;  // +inf bits
    if (i == 0) out[0] = 0.0f;
}

__global__ __launch_bounds__(BLK) void cc_min_kernel(
        const float2* __restrict__ pc,    // render points (16384)
        const float2* __restrict__ ref,   // ref points    (16384)
        unsigned int* __restrict__ ws) {
    __shared__ float4 sq[CHUNK];

    int b   = blockIdx.x;
    int dir = b / (QB * TCH);
    int rem = b % (QB * TCH);
    int qb  = rem / TCH;
    int ch  = rem % TCH;

    const float2* __restrict__ qry = dir ? ref : pc;
    const float2* __restrict__ tgt = dir ? pc  : ref;

    // Stage target chunk into LDS as (-2x, -2y, |q|^2, 0)
    for (int i = threadIdx.x; i < CHUNK; i += BLK) {
        float2 t = tgt[ch * CHUNK + i];
        sq[i] = make_float4(-2.0f * t.x, -2.0f * t.y,
                            fmaf(t.x, t.x, t.y * t.y), 0.0f);
    }
    __syncthreads();

    // Load Q queries per thread (coalesced, stride BLK)
    float px[Q], py[Q], pn[Q], m[Q];
    int qbase = qb * (BLK * Q) + threadIdx.x;
#pragma unroll
    for (int j = 0; j < Q; ++j) {
        float2 p = qry[qbase + j * BLK];
        px[j] = p.x;
        py[j] = p.y;
        pn[j] = fmaf(p.x, p.x, p.y * p.y);
        m[j]  = INFINITY;
    }

    // Inner loop: surrogate s = |q|^2 - 2qx*px - 2qy*py  (2 FMA + 1 min / pair)
#pragma unroll 8
    for (int t = 0; t < CHUNK; ++t) {
        float4 q = sq[t];   // broadcast ds_read_b128
#pragma unroll
        for (int j = 0; j < Q; ++j) {
            float s = fmaf(px[j], q.x, fmaf(py[j], q.y, q.z));
            m[j] = fminf(m[j], s);
        }
    }

    // d^2 = max(min_surrogate + |p|^2, 0); combine across chunks via atomicMin
    // (non-negative fp32 bits are order-preserving as uint)
#pragma unroll
    for (int j = 0; j < Q; ++j) {
        float d2 = fmaxf(m[j] + pn[j], 0.0f);
        atomicMin(&ws[dir * NPTS + qbase + j * BLK], __float_as_uint(d2));
    }
}

__global__ __launch_bounds__(BLK) void cc_final_kernel(
        const unsigned int* __restrict__ ws, float* __restrict__ out) {
    int i = blockIdx.x * blockDim.x + threadIdx.x;
    float s = 0.0f;
    for (int k = i; k < 2 * NPTS; k += gridDim.x * blockDim.x)
        s += sqrtf(__uint_as_float(ws[k]));

    // wave64 reduction
#pragma unroll
    for (int off = 32; off > 0; off >>= 1)
        s += __shfl_down(s, off, 64);

    __shared__ float wsum[BLK / 64];
    int lane = threadIdx.x & 63;
    int wave = threadIdx.x >> 6;
    if (lane == 0) wsum[wave] = s;
    __syncthreads();
    if (threadIdx.x == 0) {
        float bs = 0.0f;
#pragma unroll
        for (int w = 0; w < BLK / 64; ++w) bs += wsum[w];
        atomicAdd(out, bs);
    }
}

extern "C" void kernel_launch(void* const* d_in, const int* in_sizes, int n_in,
                              void* d_out, int out_size, void* d_ws, size_t ws_size,
                              hipStream_t stream) {
    const float2* pc  = (const float2*)d_in[0];  // img_render_points (128*128*2 f32)
    const float2* ref = (const float2*)d_in[1];  // ref contour (16384*2 f32)
    float* out = (float*)d_out;
    unsigned int* ws = (unsigned int*)d_ws;      // needs 2*NPTS*4 = 128 KB

    // 1) init workspace to +inf, out to 0
    cc_init_kernel<<<(2 * NPTS + BLK - 1) / BLK, BLK, 0, stream>>>(ws, out);

    // 2) pairwise min kernel: 2 dirs x 16 query-blocks x 32 chunks = 1024 blocks
    cc_min_kernel<<<2 * QB * TCH, BLK, 0, stream>>>(pc, ref, ws);

    // 3) sqrt + sum
    cc_final_kernel<<<32, BLK, 0, stream>>>(ws, out);
}